// Round 4
// baseline (34.782 us; speedup 1.0000x reference)
//
#include <hip/hip_runtime.h>
#include <math.h>

#define NT 256
#define VSTRIDE 552          // 20 zero-pad | 512 cols | 20 zero-pad  (stride*4B is 16B-aligned)

// ---- K1: vertical sliding-35 max of y = 1 - min_c(x), direct from global ----
// Computed as 1 - (sliding MIN of m = min_c(x)); OOB-row pad m=1 (min-neutral, x<1).
// 1024 blocks: (batch b, 16-row chunk t, col half). Thread owns 1 col x 16 out rows.
// All loads unconditional (rows clamped) -> straight-line code, deep load batching.
__global__ __launch_bounds__(NT, 4)
void dark_vpass(const float* __restrict__ x, float* __restrict__ V) {
    const int tid = threadIdx.x;
    const int bid = blockIdx.x;
    const int swz = (bid & 7) * 128 + (bid >> 3);   // XCD k -> batches 2k,2k+1
    const int b    = swz >> 6;
    const int rest = swz & 63;
    const int t    = rest >> 1;                      // out rows 16t..16t+15
    const int col  = (rest & 1) * 256 + tid;         // lanes consecutive -> coalesced
    const float* xb = x + (size_t)b * 786432u + col;
    float* vb = V + (size_t)b * (512 * VSTRIDE);

    float w[50];
    #pragma unroll
    for (int k = 0; k < 50; ++k) {
        const int gh  = 16 * t - 17 + k;
        const int ghc = gh < 0 ? 0 : (gh > 511 ? 511 : gh);   // clamp: loads stay unconditional
        const float* p = xb + ghc * 512;
        const float m = fminf(p[0], fminf(p[262144], p[524288]));
        w[k] = ((unsigned)gh < 512u) ? m : 1.0f;              // select, not branch
    }
    // sliding MIN over window 35 via doubling: min32 then combine at offset 3
    #pragma unroll
    for (int i = 0; i <= 48; ++i) w[i] = fminf(w[i], w[i + 1]);
    #pragma unroll
    for (int i = 0; i <= 46; ++i) w[i] = fminf(w[i], w[i + 2]);
    #pragma unroll
    for (int i = 0; i <= 42; ++i) w[i] = fminf(w[i], w[i + 4]);
    #pragma unroll
    for (int i = 0; i <= 34; ++i) w[i] = fminf(w[i], w[i + 8]);
    #pragma unroll
    for (int i = 0; i <= 18; ++i) w[i] = fminf(w[i], w[i + 16]);

    #pragma unroll
    for (int kk = 0; kk < 16; ++kk)
        vb[(16 * t + kk) * VSTRIDE + 20 + col] = 1.0f - fminf(w[kk], w[kk + 3]);
    if (col < 20) {                                  // zero left pad (max-neutral for K2)
        #pragma unroll
        for (int kk = 0; kk < 16; ++kk) vb[(16 * t + kk) * VSTRIDE + col] = 0.0f;
    }
    if (col >= 492) {                                // zero right pad (532..551)
        #pragma unroll
        for (int kk = 0; kk < 16; ++kk) vb[(16 * t + kk) * VSTRIDE + col + 40] = 0.0f;
    }
}

// ---- K2: horizontal sliding-35 max + partial sum. Thread owns 1 row x 16 out cols ----
// Buffer col i maps to image col i-20; window for out col j is buffer [j+3, j+37].
__global__ __launch_bounds__(NT, 4)
void dark_hpass(const float* __restrict__ V, float* __restrict__ part) {
    const int tid = threadIdx.x;
    const int bid = blockIdx.x;
    const int swz = (bid & 7) * 128 + (bid >> 3);    // same mapping as K1 -> L2-local V reuse
    const int b   = swz >> 6;
    const int rg  = swz & 63;
    const int row = rg * 8 + (tid >> 5);
    const int c   = tid & 31;                        // 16-col output chunk
    const float* vrow = V + (size_t)b * (512 * VSTRIDE) + row * VSTRIDE + 16 * c;

    float w[56];
    #pragma unroll
    for (int i = 0; i < 14; ++i) {
        const float4 q = *(const float4*)(vrow + 4 * i);
        w[4*i] = q.x; w[4*i+1] = q.y; w[4*i+2] = q.z; w[4*i+3] = q.w;
    }
    #pragma unroll
    for (int i = 3; i <= 51; ++i) w[i] = fmaxf(w[i], w[i + 1]);
    #pragma unroll
    for (int i = 3; i <= 49; ++i) w[i] = fmaxf(w[i], w[i + 2]);
    #pragma unroll
    for (int i = 3; i <= 45; ++i) w[i] = fmaxf(w[i], w[i + 4]);
    #pragma unroll
    for (int i = 3; i <= 37; ++i) w[i] = fmaxf(w[i], w[i + 8]);
    #pragma unroll
    for (int i = 3; i <= 21; ++i) w[i] = fmaxf(w[i], w[i + 16]);
    float s = 0.0f;
    #pragma unroll
    for (int kk = 0; kk < 16; ++kk) s += fmaxf(w[3 + kk], w[6 + kk]);   // dc >= 0, |.| free

    #pragma unroll
    for (int off = 32; off; off >>= 1) s += __shfl_down(s, off);
    __shared__ float red[4];
    if ((tid & 63) == 0) red[tid >> 6] = s;
    __syncthreads();
    if (tid == 0) part[bid] = red[0] + red[1] + red[2] + red[3];
}

__global__ void dark_reduce(const float* __restrict__ part, float* __restrict__ out, int n) {
    float s = 0.0f;
    for (int i = threadIdx.x; i < n; i += NT) s += part[i];
    #pragma unroll
    for (int off = 32; off; off >>= 1) s += __shfl_down(s, off);
    __shared__ float w[NT / 64];
    if ((threadIdx.x & 63) == 0) w[threadIdx.x >> 6] = s;
    __syncthreads();
    if (threadIdx.x == 0) {
        float t = 0.0f;
        #pragma unroll
        for (int i = 0; i < NT / 64; ++i) t += w[i];
        out[0] = -t * (1.0f / 4194304.0f);   // -mean over 16*512*512
    }
}

extern "C" void kernel_launch(void* const* d_in, const int* in_sizes, int n_in,
                              void* d_out, int out_size, void* d_ws, size_t ws_size,
                              hipStream_t stream) {
    const float* x = (const float*)d_in[0];
    float* out  = (float*)d_out;
    float* part = (float*)d_ws;                       // 1024 floats
    float* V    = (float*)((char*)d_ws + 4096);       // 16*512*VSTRIDE f32 = 18.1 MB

    hipLaunchKernelGGL(dark_vpass,  dim3(1024), dim3(NT), 0, stream, x, V);
    hipLaunchKernelGGL(dark_hpass,  dim3(1024), dim3(NT), 0, stream, V, part);
    hipLaunchKernelGGL(dark_reduce, dim3(1), dim3(NT), 0, stream, part, out, 1024);
}